// Round 11
// baseline (3514.617 us; speedup 1.0000x reference)
//
#include <hip/hip_runtime.h>
#include <math.h>

typedef unsigned short u16;
typedef __attribute__((ext_vector_type(8))) short s8v;   // 8 x bf16 (4 VGPRs)
typedef __attribute__((ext_vector_type(4))) float f4v;   // MFMA accumulator
typedef __attribute__((ext_vector_type(4))) int   i4v;   // asm load payload

constexpr int kB    = 256;
constexpr int kT    = 512;
constexpr int kDIN  = 64;
constexpr int kH    = 512;
constexpr int kG3   = 1536;
constexpr int kNOUT = 128;
constexpr int kPlane = 8 * 2 * 16 * 512;   // u16 per A-frag plane (131072)

__device__ __forceinline__ u16 f2bf(float f) {   // round-to-nearest-even
  union { float f; unsigned u; } v; v.f = f;
  unsigned r = (v.u + 0x7FFFu + ((v.u >> 16) & 1u)) >> 16;
  return (u16)r;
}
__device__ __forceinline__ float bf2f(u16 u) {
  union { unsigned u; float f; } v; v.u = ((unsigned)u) << 16; return v.f;
}
__device__ __forceinline__ float fsig(float x) {
  x = fminf(fmaxf(x, -30.f), 30.f);
  float e = __expf(-x);
  return __fdividef(1.f, 1.f + e);
}
__device__ __forceinline__ float ftanh(float x) {
  x = fminf(fmaxf(x, -15.f), 15.f);
  float e = __expf(-2.f * x);
  return __fdividef(1.f - e, 1.f + e);
}

// 16 A-fragment loads (16 B/lane each, kt stride 1024 B), L1/L2 bypass to the
// LLC coherency point; one vmcnt(0) at the end — full MLP. (R8/R9-proven.)
__device__ __forceinline__ void load_afrag16(const u16* base, i4v a[16]) {
  asm volatile(
      "global_load_dwordx4 %0, %16, off sc0 sc1\n\t"
      "global_load_dwordx4 %1, %16, off offset:1024 sc0 sc1\n\t"
      "global_load_dwordx4 %2, %16, off offset:2048 sc0 sc1\n\t"
      "global_load_dwordx4 %3, %16, off offset:3072 sc0 sc1\n\t"
      "global_load_dwordx4 %4, %17, off sc0 sc1\n\t"
      "global_load_dwordx4 %5, %17, off offset:1024 sc0 sc1\n\t"
      "global_load_dwordx4 %6, %17, off offset:2048 sc0 sc1\n\t"
      "global_load_dwordx4 %7, %17, off offset:3072 sc0 sc1\n\t"
      "global_load_dwordx4 %8, %18, off sc0 sc1\n\t"
      "global_load_dwordx4 %9, %18, off offset:1024 sc0 sc1\n\t"
      "global_load_dwordx4 %10, %18, off offset:2048 sc0 sc1\n\t"
      "global_load_dwordx4 %11, %18, off offset:3072 sc0 sc1\n\t"
      "global_load_dwordx4 %12, %19, off sc0 sc1\n\t"
      "global_load_dwordx4 %13, %19, off offset:1024 sc0 sc1\n\t"
      "global_load_dwordx4 %14, %19, off offset:2048 sc0 sc1\n\t"
      "global_load_dwordx4 %15, %19, off offset:3072 sc0 sc1\n\t"
      "s_waitcnt vmcnt(0)"
      : "=&v"(a[0]), "=&v"(a[1]), "=&v"(a[2]), "=&v"(a[3]),
        "=&v"(a[4]), "=&v"(a[5]), "=&v"(a[6]), "=&v"(a[7]),
        "=&v"(a[8]), "=&v"(a[9]), "=&v"(a[10]), "=&v"(a[11]),
        "=&v"(a[12]), "=&v"(a[13]), "=&v"(a[14]), "=&v"(a[15])
      : "v"(base), "v"(base + 4 * 512), "v"(base + 8 * 512), "v"(base + 12 * 512)
      : "memory");
}

// Layer-0 epilogue stores: 4 LLC-coherent hbuf stores FIRST, then 4 plain
// h1seq stores, then vmcnt(4) — waits only for the hbuf (oldest) 4; h1seq
// drains during the barrier round (vmcnt retires in issue order).
__device__ __forceinline__ void store_h_l0(
    u16* p0, u16* p1, u16* p2, u16* p3,
    u16* q0, u16* q1, u16* q2, u16* q3,
    unsigned v0, unsigned v1, unsigned v2, unsigned v3) {
  asm volatile(
      "global_store_short %0, %8, off sc0 sc1\n\t"
      "global_store_short %1, %9, off sc0 sc1\n\t"
      "global_store_short %2, %10, off sc0 sc1\n\t"
      "global_store_short %3, %11, off sc0 sc1\n\t"
      "global_store_short %4, %8, off\n\t"
      "global_store_short %5, %9, off\n\t"
      "global_store_short %6, %10, off\n\t"
      "global_store_short %7, %11, off\n\t"
      "s_waitcnt vmcnt(4)"
      :: "v"(p0), "v"(p1), "v"(p2), "v"(p3),
         "v"(q0), "v"(q1), "v"(q2), "v"(q3),
         "v"(v0), "v"(v1), "v"(v2), "v"(v3)
      : "memory");
}
// Layer-1: 4 coherent stores + full drain.
__device__ __forceinline__ void store_h_l1(
    u16* p0, u16* p1, u16* p2, u16* p3,
    unsigned v0, unsigned v1, unsigned v2, unsigned v3) {
  asm volatile(
      "global_store_short %0, %4, off sc0 sc1\n\t"
      "global_store_short %1, %5, off sc0 sc1\n\t"
      "global_store_short %2, %6, off sc0 sc1\n\t"
      "global_store_short %3, %7, off sc0 sc1\n\t"
      "s_waitcnt vmcnt(0)"
      :: "v"(p0), "v"(p1), "v"(p2), "v"(p3),
         "v"(v0), "v"(v1), "v"(v2), "v"(v3)
      : "memory");
}

// ---------------------------------------------------------------------------
// Pre-swizzle w_hh [1536][512] fp32 -> per-block-slice B-fragment slabs (bf16).
// Slab layout: [jt 16][f 96][lane 64][8],  f = nt*16 + kt,  nt = g*2 + u.
// ---------------------------------------------------------------------------
__global__ void build_wslab(const float* __restrict__ w, u16* __restrict__ d) {
  int idx  = blockIdx.x * 256 + threadIdx.x;   // 0..98303
  int lane = idx & 63, fg = idx >> 6;          // fg = jt*96 + f
  int jt = fg / 96, f = fg % 96;
  int nt = f >> 4, kt = f & 15;
  int g = nt >> 1, u = nt & 1;
  int row = g * 512 + jt * 32 + u * 16 + (lane & 15);
  int k0  = kt * 32 + (lane >> 4) * 8;
  const float* src = w + (size_t)row * 512 + k0;
  u16* dst = d + ((size_t)fg) * 512 + lane * 8;
#pragma unroll
  for (int i = 0; i < 8; i++) dst[i] = f2bf(src[i]);
}

// ---------------------------------------------------------------------------
// Recurrence role (R9-proven structure; xg now bf16). One block = (layer,
// bt, jt): 32 batches x 32 j, 4 waves. Weights resident (48 B-frags/wave).
// h exchange via LLC-coherent hbuf planes; split-phase group barrier.
// ---------------------------------------------------------------------------
__device__ void rec_role(int layer, int TC, unsigned bar_base16,
                         unsigned* mybar, int bt, int jt,
                         const u16* __restrict__ xg,
                         const u16* __restrict__ wslab,
                         const float* __restrict__ bhh,
                         u16* __restrict__ h1p,      // null for layer 1
                         u16* __restrict__ hbuf, float* __restrict__ carry) {
  float* mycarry = carry + (size_t)layer * kB * kH;

  const int tid  = threadIdx.x;
  const int wv   = tid >> 6, lane = tid & 63;
  const int mt   = wv >> 1, u = wv & 1;
  const int b0   = bt * 32;
  const int jl   = lane & 15;
  const int jg   = jt * 32 + u * 16 + jl;        // this lane's output j
  const int mrow = (lane >> 4) * 4;              // first of 4 batch rows

  // --- load this wave's 48 B-fragments into registers (once) ---
  s8v bfr[3][16];
  {
    const u16* base = wslab + (size_t)jt * 96 * 512;
#pragma unroll
    for (int g = 0; g < 3; ++g)
#pragma unroll
      for (int kt = 0; kt < 16; ++kt)
        bfr[g][kt] = *(const s8v*)&base[(size_t)((g * 2 + u) * 16 + kt) * 512 + lane * 8];
  }
  const float bh_r = bhh[jg], bh_z = bhh[512 + jg], bh_n = bhh[1024 + jg];

  // --- fp32 state for this lane's 4 (batch, j) outputs, from carry ---
  float hp[4];
#pragma unroll
  for (int r = 0; r < 4; ++r)
    hp[r] = mycarry[(size_t)(b0 + mt * 16 + mrow + r) * 512 + jg];

  const size_t cons_off = ((size_t)((bt * 2 + mt) * 16)) * 512 + lane * 8;
  const size_t prod_off = ((size_t)((bt * 2 + mt) * 16 + jt)) * 512 +
                          (size_t)(16 * (u * 2 + (jl >> 3))) * 8 + (jl & 7);
  const int bbase = b0 + mt * 16 + mrow;   // first batch row of this lane

  u16 xu0[4], xu1[4], xu2[4];
  auto prefetch_xg = [&](int tt) {
#pragma unroll
    for (int r = 0; r < 4; ++r) {
      const u16* xp = xg + ((size_t)(bbase + r) * TC + tt) * kG3;
      xu0[r] = xp[jg]; xu1[r] = xp[512 + jg]; xu2[r] = xp[1024 + jg];
    }
  };
  prefetch_xg(0);

  for (int t = 0; t < TC; ++t) {
    // --- wait phase: all step-(t-1) publishes visible (no-op at t==0) ---
    if (tid == 0) {
      unsigned tgt = bar_base16 + 16u * (unsigned)t;
      int guard = 0;
      while (__hip_atomic_load(mybar, __ATOMIC_RELAXED,
                               __HIP_MEMORY_SCOPE_AGENT) < tgt
             && ++guard < (1 << 21)) {
        __builtin_amdgcn_s_sleep(1);
      }
    }
    __syncthreads();

    // --- A-fragments of h_{t-1}; vmcnt(0) also drains the xg prefetch ---
    const u16* plane = hbuf + (size_t)(layer * 2 + (t & 1)) * kPlane;
    i4v a[16];
    load_afrag16(plane + cons_off, a);

    // --- MFMA: 3 gates x 16 k-tiles (3 independent chains) ---
    f4v acc0 = {0.f, 0.f, 0.f, 0.f}, acc1 = acc0, acc2 = acc0;
#pragma unroll
    for (int kt = 0; kt < 16; ++kt) {
      const s8v av = __builtin_bit_cast(s8v, a[kt]);
      acc0 = __builtin_amdgcn_mfma_f32_16x16x32_bf16(av, bfr[0][kt], acc0, 0, 0, 0);
      acc1 = __builtin_amdgcn_mfma_f32_16x16x32_bf16(av, bfr[1][kt], acc1, 0, 0, 0);
      acc2 = __builtin_amdgcn_mfma_f32_16x16x32_bf16(av, bfr[2][kt], acc2, 0, 0, 0);
    }

    // --- gates + state update ---
    unsigned hv[4];
#pragma unroll
    for (int r = 0; r < 4; ++r) {
      float rr = fsig(bf2f(xu0[r]) + acc0[r] + bh_r);
      float zz = fsig(bf2f(xu1[r]) + acc1[r] + bh_z);
      float nn = ftanh(bf2f(xu2[r]) + rr * (acc2[r] + bh_n));
      float hn = (1.f - zz) * nn + zz * hp[r];
      hp[r] = hn;
      hv[r] = f2bf(hn);
    }

    // --- publish h_t (hbuf coherent; h1seq trailing) ---
    u16* pb = hbuf + (size_t)(layer * 2 + ((t + 1) & 1)) * kPlane + prod_off;
    if (layer == 0) {
      u16* q = h1p + ((size_t)bbase * TC + t) * 512 + jg;
      store_h_l0(pb + (size_t)(mrow + 0) * 8, pb + (size_t)(mrow + 1) * 8,
                 pb + (size_t)(mrow + 2) * 8, pb + (size_t)(mrow + 3) * 8,
                 q, q + (size_t)TC * 512, q + 2 * (size_t)TC * 512,
                 q + 3 * (size_t)TC * 512,
                 hv[0], hv[1], hv[2], hv[3]);
    } else {
      store_h_l1(pb + (size_t)(mrow + 0) * 8, pb + (size_t)(mrow + 1) * 8,
                 pb + (size_t)(mrow + 2) * 8, pb + (size_t)(mrow + 3) * 8,
                 hv[0], hv[1], hv[2], hv[3]);
    }
    __syncthreads();                 // all waves' publishes drained
    if (tid == 0)
      __hip_atomic_fetch_add(mybar, 1u, __ATOMIC_RELAXED,
                             __HIP_MEMORY_SCOPE_AGENT);
    if (t + 1 < TC) prefetch_xg(t + 1);   // flies during next wait phase
  }

  // --- carry writeback (fp32) ---
#pragma unroll
  for (int r = 0; r < 4; ++r)
    mycarry[(size_t)(bbase + r) * 512 + jg] = hp[r];
}

// ---------------------------------------------------------------------------
// 256-thread GEMM role, tile 64(m) x 128(n), BK=32, bf16 MFMA, bf16 OUT.
// C[r][1536] = A[r][K] @ W[1536][K]^T + bias; row r -> (b=r/TC, t=r%TC),
// A rowptr = A + (b*Abstride + Atoff + t)*K;  C addr = r*1536 + n (bf16).
// ---------------------------------------------------------------------------
__device__ void gemm64x128(int idx, int TC,
                           const float* __restrict__ Af, const u16* __restrict__ Ab,
                           int Abstride, int Atoff, int K,
                           const float* __restrict__ W, const float* __restrict__ bias,
                           u16* __restrict__ Cb, char* smem) {
  u16* As = (u16*)smem;            // [64][40]
  u16* Bs = As + 64 * 40;          // [128][40]
  const int tid = threadIdx.x;
  const int mt = idx / 12, nt = idx % 12;
  const int m0 = mt * 64, n0 = nt * 128;
  const int w = tid >> 6, lane = tid & 63;
  const int ra = tid >> 2, koff = (tid & 3) * 8;

  const int r = m0 + ra;
  const size_t aoff = ((size_t)(r / TC) * Abstride + Atoff + (r % TC)) * K;
  const float* arowF = Af ? Af + aoff : nullptr;
  const u16*  arowB = Ab ? Ab + aoff : nullptr;
  const float* brow0 = W + (size_t)(n0 + ra) * K;
  const float* brow1 = W + (size_t)(n0 + ra + 64) * K;

  f4v acc[4][2];
#pragma unroll
  for (int i = 0; i < 4; i++)
#pragma unroll
    for (int jn = 0; jn < 2; jn++) acc[i][jn] = (f4v){0.f, 0.f, 0.f, 0.f};

  for (int k0 = 0; k0 < K; k0 += 32) {
    s8v av, bv0, bv1;
    if (arowB) {
      av = *(const s8v*)(arowB + k0 + koff);
    } else {
      u16 tmp[8];
      const float* ap = arowF + k0 + koff;
#pragma unroll
      for (int i = 0; i < 8; i++) tmp[i] = f2bf(ap[i]);
      av = *(s8v*)tmp;
    }
    {
      u16 t0[8], t1[8];
      const float* bp0 = brow0 + k0 + koff;
      const float* bp1 = brow1 + k0 + koff;
#pragma unroll
      for (int i = 0; i < 8; i++) { t0[i] = f2bf(bp0[i]); t1[i] = f2bf(bp1[i]); }
      bv0 = *(s8v*)t0; bv1 = *(s8v*)t1;
    }
    __syncthreads();
    *(s8v*)&As[ra * 40 + koff] = av;
    *(s8v*)&Bs[ra * 40 + koff] = bv0;
    *(s8v*)&Bs[(ra + 64) * 40 + koff] = bv1;
    __syncthreads();
    s8v af[4];
#pragma unroll
    for (int i = 0; i < 4; i++)
      af[i] = *(const s8v*)&As[(i * 16 + (lane & 15)) * 40 + (lane >> 4) * 8];
#pragma unroll
    for (int jn = 0; jn < 2; jn++) {
      s8v bf = *(const s8v*)&Bs[(w * 32 + jn * 16 + (lane & 15)) * 40 + (lane >> 4) * 8];
#pragma unroll
      for (int i = 0; i < 4; i++)
        acc[i][jn] = __builtin_amdgcn_mfma_f32_16x16x32_bf16(af[i], bf, acc[i][jn], 0, 0, 0);
    }
  }

#pragma unroll
  for (int jn = 0; jn < 2; jn++) {
    int n = n0 + w * 32 + jn * 16 + (lane & 15);
    float bv2 = bias[n];
#pragma unroll
    for (int i = 0; i < 4; i++) {
      int mr = m0 + i * 16 + (lane >> 4) * 4;
#pragma unroll
      for (int reg = 0; reg < 4; reg++)
        Cb[(size_t)(mr + reg) * kG3 + n] = f2bf(acc[i][jn][reg] + bv2);
    }
  }
}

// ---------------------------------------------------------------------------
// Fused dispatch c: blocks [0,256) recurrence (rec0(c), rec1(c-2)),
// [256, 256+G1) proj1(c-1), [256+G1, 256+2*G1) proj0(c+1). G1 = 48*TC.
// All xg/h1seq parity-paired: rec reads parity c&1; gemms write 1-(c&1).
// ---------------------------------------------------------------------------
__global__ __launch_bounds__(256, 1)
void mega(int c, int TC, int nc, unsigned bar_base16, unsigned* bar,
          const float* __restrict__ x,
          u16* __restrict__ xg0, u16* __restrict__ xg1,
          u16* __restrict__ h1seq,
          const u16* __restrict__ wslab0, const u16* __restrict__ wslab1,
          const float* __restrict__ bhh0, const float* __restrict__ bhh1,
          const float* __restrict__ wih0, const float* __restrict__ bih0,
          const float* __restrict__ wih1, const float* __restrict__ bih1,
          u16* __restrict__ hbuf, float* __restrict__ carry) {
  __shared__ __align__(16) char smem[(64 + 128) * 40 * 2];
  const int bid = blockIdx.x;
  const int G1  = 48 * TC;
  const size_t xgChunk = (size_t)kB * TC * kG3;
  const size_t h1Chunk = (size_t)kB * TC * kH;
  const int par = c & 1;

  if (bid < 256) {
    const int layer = bid >> 7;
    const int lb    = bid & 127;
    const int jt    = lb & 15, bt = lb >> 4;
    const int cc    = layer ? c - 2 : c;
    unsigned* mybar = bar + (size_t)(layer * 8 + bt) * 64;
    if (cc < 0 || cc >= nc) {   // keep the group's counter in lockstep
      if (threadIdx.x == 0)
        __hip_atomic_fetch_add(mybar, (unsigned)TC, __ATOMIC_RELAXED,
                               __HIP_MEMORY_SCOPE_AGENT);
      return;
    }
    const u16* xg = (layer ? xg1 : xg0) + (size_t)par * xgChunk;
    u16* h1p = (layer == 0) ? (h1seq + (size_t)par * h1Chunk) : nullptr;
    rec_role(layer, TC, bar_base16, mybar, bt, jt, xg,
             layer ? wslab1 : wslab0, layer ? bhh1 : bhh0,
             h1p, hbuf, carry);
  } else if (bid < 256 + G1) {
    const int cc = c - 1;                // proj1(c-1): h1seq -> xg1
    if (cc < 0 || cc >= nc) return;
    gemm64x128(bid - 256, TC, nullptr, h1seq + (size_t)(cc & 1) * h1Chunk,
               TC, 0, kH, wih1, bih1, xg1 + (size_t)(cc & 1) * xgChunk, smem);
  } else {
    const int cc = c + 1;                // proj0(c+1): x -> xg0
    if (cc < 1 || cc >= nc) return;      // chunk 0 done in prologue
    gemm64x128(bid - 256 - G1, TC, x, nullptr, kT, cc * TC, kDIN,
               wih0, bih0, xg0 + (size_t)(cc & 1) * xgChunk, smem);
  }
}

// Prologue proj0(0) -> xg0 parity 0
__global__ __launch_bounds__(256)
void proj0_kernel(int TC, const float* __restrict__ x,
                  const float* __restrict__ wih0, const float* __restrict__ bih0,
                  u16* __restrict__ xg0) {
  __shared__ __align__(16) char smem[(64 + 128) * 40 * 2];
  gemm64x128(blockIdx.x, TC, x, nullptr, kT, 0, kDIN, wih0, bih0, xg0, smem);
}

// ---------------------------------------------------------------------------
__global__ __launch_bounds__(128)
void fc_kernel(const float* __restrict__ h, const float* __restrict__ wfc,
               const float* __restrict__ bfc, float* __restrict__ out) {
  const int b = blockIdx.x;
  const int n = threadIdx.x;
  const float* hrow = h + (size_t)b * kH;
  const float* wrow = wfc + (size_t)n * kH;
  float acc = 0.f;
#pragma unroll 4
  for (int k = 0; k < kH; k += 4) {
    const float4 hv = *(const float4*)&hrow[k];
    const float4 wv = *(const float4*)&wrow[k];
    acc = fmaf(hv.x, wv.x, acc); acc = fmaf(hv.y, wv.y, acc);
    acc = fmaf(hv.z, wv.z, acc); acc = fmaf(hv.w, wv.w, acc);
  }
  out[(size_t)b * kNOUT + n] = acc + bfc[n];
}

// ---------------------------------------------------------------------------
extern "C" void kernel_launch(void* const* d_in, const int* in_sizes, int n_in,
                              void* d_out, int out_size, void* d_ws, size_t ws_size,
                              hipStream_t stream) {
  const float* x     = (const float*)d_in[0];
  const float* w_ih0 = (const float*)d_in[1];
  const float* w_hh0 = (const float*)d_in[2];
  const float* b_ih0 = (const float*)d_in[3];
  const float* b_hh0 = (const float*)d_in[4];
  const float* w_ih1 = (const float*)d_in[5];
  const float* w_hh1 = (const float*)d_in[6];
  const float* b_ih1 = (const float*)d_in[7];
  const float* b_hh1 = (const float*)d_in[8];
  const float* w_fc  = (const float*)d_in[9];
  const float* b_fc  = (const float*)d_in[10];
  float* out = (float*)d_out;

  // workspace sizing (TC adaptive; TC=64 needs ~240 MB; R3 proved ws >= ~440 MB)
  auto need = [](int tc) -> size_t {
    size_t s = 0;
    s += 2 * (size_t)kB * tc * kG3 * 2;   // xg0 bf16 parity pair
    s += 2 * (size_t)kB * tc * kG3 * 2;   // xg1 bf16 parity pair
    s += 2 * (size_t)kB * tc * kH * 2;    // h1seq bf16 parity pair
    s += 2 * (size_t)kG3 * kH * 2;        // wslab x2
    s += 4 * (size_t)kPlane * 2;          // hbuf planes [2 layers][2 parity]
    s += 2 * (size_t)kB * kH * 4;         // carry fp32 x2
    s += 32768;
    return s;
  };
  int TC = 64;
  while (TC > 2 && need(TC) > ws_size) TC >>= 1;
  const int nc = kT / TC;

  char* p = (char*)d_ws;
  auto carve = [&](size_t bytes) {
    char* r = p; p += (bytes + 255) & ~(size_t)255; return r;
  };
  u16* xg0     = (u16*)carve(2 * (size_t)kB * TC * kG3 * 2);
  u16* xg1     = (u16*)carve(2 * (size_t)kB * TC * kG3 * 2);
  u16* h1seq   = (u16*)carve(2 * (size_t)kB * TC * kH * 2);
  u16* wslab0  = (u16*)carve((size_t)kG3 * kH * 2);
  u16* wslab1  = (u16*)carve((size_t)kG3 * kH * 2);
  u16* hbuf    = (u16*)carve(4 * (size_t)kPlane * 2);
  float* carry = (float*)carve(2 * (size_t)kB * kH * 4);
  unsigned* bar = (unsigned*)carve(32 * 64 * sizeof(unsigned));  // 32 cachelines

  // prologue: weight swizzle + zero h planes/carries + barrier counters
  build_wslab<<<384, 256, 0, stream>>>(w_hh0, wslab0);
  build_wslab<<<384, 256, 0, stream>>>(w_hh1, wslab1);
  hipMemsetAsync(hbuf, 0, 4 * (size_t)kPlane * 2 + 2 * (size_t)kB * kH * 4, stream);
  hipMemsetAsync(bar, 0, 32 * 64 * sizeof(unsigned), stream);

  // proj0(0) -> xg0 parity 0
  proj0_kernel<<<dim3(48 * TC), 256, 0, stream>>>(TC, x, w_ih0, b_ih0, xg0);

  const dim3 grid(256 + 2 * 48 * TC);
  for (int c = 0; c <= nc + 1; ++c) {
    unsigned base16 = (unsigned)c * 16u * (unsigned)TC;
    mega<<<grid, 256, 0, stream>>>(
        c, TC, nc, base16, bar, x, xg0, xg1, h1seq,
        wslab0, wslab1, b_hh0, b_hh1,
        w_ih0, b_ih0, w_ih1, b_ih1, hbuf, carry);
  }

  // final FC on layer-1 carry (fp32)
  fc_kernel<<<dim3(kB), dim3(kNOUT), 0, stream>>>(
      carry + (size_t)kB * kH, w_fc, b_fc, out);
}